// Round 3
// baseline (2284.115 us; speedup 1.0000x reference)
//
#include <hip/hip_runtime.h>
#include <hip/hip_bf16.h>

#define BB 4
#define CC 128
#define CQ 16
#define TDIM 16
#define WDIM 64
#define HDIM 64
#define SS 65536            /* T*W*H */
#define CS (CC*SS)          /* per-batch elements: 8388608 */

typedef unsigned short u16;
typedef unsigned int   u32;

__device__ __forceinline__ float bf2f(u16 v) { return __uint_as_float(((u32)v) << 16); }
__device__ __forceinline__ u16 f2bf(float f) {
    u32 u = __float_as_uint(f);
    u32 r = (u + 0x7fffu + ((u >> 16) & 1u)) >> 16;
    return (u16)r;
}
__device__ __forceinline__ void unpack8(uint4 r, float* f) {
    f[0] = __uint_as_float(r.x << 16); f[1] = __uint_as_float(r.x & 0xffff0000u);
    f[2] = __uint_as_float(r.y << 16); f[3] = __uint_as_float(r.y & 0xffff0000u);
    f[4] = __uint_as_float(r.z << 16); f[5] = __uint_as_float(r.z & 0xffff0000u);
    f[6] = __uint_as_float(r.w << 16); f[7] = __uint_as_float(r.w & 0xffff0000u);
}

// ---------------------------------------------------------------------------
// Kernel A: QKV 1x1 conv for ONE batch (all fp32 I/O).
// q,k -> fp32 (cq, S); v -> bf16 (c, S) in workspace.
// One block = 64 positions; fp32 x tile in LDS (32 KB); weights read from
// global (L2-resident, 8 lanes share each address).  Each thread: 5 output
// rows x 8 consecutive positions.
// ---------------------------------------------------------------------------
__global__ __launch_bounds__(256) void qkv_kernel(
    const float* __restrict__ xb,
    const float* __restrict__ Wq, const float* __restrict__ bq,
    const float* __restrict__ Wk, const float* __restrict__ bk,
    const float* __restrict__ Wv, const float* __restrict__ bv,
    float* __restrict__ qf, float* __restrict__ kf, u16* __restrict__ vf)
{
    __shared__ float lx[128 * 64];     // 32 KB
    const int t  = threadIdx.x;
    const int s0 = blockIdx.x << 6;    // 1024 blocks per batch

    for (int idx = t; idx < 128 * 64; idx += 256) {
        int c = idx >> 6, p = idx & 63;
        lx[idx] = xb[(size_t)c * SS + s0 + p];
    }
    __syncthreads();

    const int p8 = (t & 7) * 8;
    const int og = t >> 3;   // 0..31

    // per-thread weight-row pointers + biases for the 5 output rows
    const float* wrow[5];
    float acc[5][8];
    {
        const float* w0 = (og < 16) ? (Wq + og * 128) : (Wk + (og - 16) * 128);
        float b0 = (og < 16) ? bq[og] : bk[og - 16];
        wrow[0] = w0;
#pragma unroll
        for (int j = 0; j < 8; j++) acc[0][j] = b0;
#pragma unroll
        for (int r = 1; r < 5; r++) {
            int vrow = og + 32 * (r - 1);
            wrow[r] = Wv + vrow * 128;
            float bias = bv[vrow];
#pragma unroll
            for (int j = 0; j < 8; j++) acc[r][j] = bias;
        }
    }

    for (int cb = 0; cb < 32; cb++) {
        float xv[32];
#pragma unroll
        for (int cc2 = 0; cc2 < 4; cc2++) {
            float4 raw = *(const float4*)(&lx[(cb * 4 + cc2) * 64 + p8]);
            xv[cc2 * 8 + 0] = raw.x; xv[cc2 * 8 + 1] = raw.y;
            xv[cc2 * 8 + 2] = raw.z; xv[cc2 * 8 + 3] = raw.w;
            float4 rw = *(const float4*)(&lx[(cb * 4 + cc2) * 64 + p8 + 4]);
            xv[cc2 * 8 + 4] = rw.x; xv[cc2 * 8 + 5] = rw.y;
            xv[cc2 * 8 + 6] = rw.z; xv[cc2 * 8 + 7] = rw.w;
        }
#pragma unroll
        for (int r = 0; r < 5; r++) {
            float4 wr = *(const float4*)(wrow[r] + cb * 4);
#pragma unroll
            for (int j = 0; j < 8; j++)
                acc[r][j] += wr.x * xv[j] + wr.y * xv[8 + j]
                           + wr.z * xv[16 + j] + wr.w * xv[24 + j];
        }
    }

    // r = 0: q or k row (fp32)
    {
        float* dst = (og < 16) ? (qf + (size_t)og * SS + s0 + p8)
                               : (kf + (size_t)(og - 16) * SS + s0 + p8);
        *(float4*)(dst)     = make_float4(acc[0][0], acc[0][1], acc[0][2], acc[0][3]);
        *(float4*)(dst + 4) = make_float4(acc[0][4], acc[0][5], acc[0][6], acc[0][7]);
    }
    // r = 1..4: v rows (bf16 in workspace)
#pragma unroll
    for (int r = 1; r < 5; r++) {
        int vrow = og + 32 * (r - 1);
        u16* dst = vf + (size_t)vrow * SS + s0 + p8;
        uint4 pk;
        pk.x = (u32)f2bf(acc[r][0]) | ((u32)f2bf(acc[r][1]) << 16);
        pk.y = (u32)f2bf(acc[r][2]) | ((u32)f2bf(acc[r][3]) << 16);
        pk.z = (u32)f2bf(acc[r][4]) | ((u32)f2bf(acc[r][5]) << 16);
        pk.w = (u32)f2bf(acc[r][6]) | ((u32)f2bf(acc[r][7]) << 16);
        *(uint4*)dst = pk;
    }
}

// ---------------------------------------------------------------------------
__global__ void zero_kernel(float* __restrict__ p, int n)
{
    int i = blockIdx.x * 256 + threadIdx.x;
    if (i < n) p[i] = 0.f;
}

// ---------------------------------------------------------------------------
// Kernel B: attn logits for ONE batch.  logits[a1][a2] = sum_n q[a1*N+n]*k[n*A+a2]
// (raw-reshape views of per-batch flat q/k).  NC=64 chunk + fp32 atomicAdd.
// ---------------------------------------------------------------------------
template <int A>
__global__ __launch_bounds__(256) void attn_logits_kernel(
    const float* __restrict__ qb, const float* __restrict__ kb,
    float* __restrict__ logits)
{
    constexpr int NC = 64;
    constexpr int N = (CQ * SS) / A;
    __shared__ float qs[A][NC + 1];
    __shared__ float ks[NC][A];
    const int t  = threadIdx.x;
    const int n0 = blockIdx.x * NC;      // grid = N/NC blocks

    for (int idx = t; idx < A * NC; idx += 256) {
        int a1 = idx >> 6, n = idx & 63;
        qs[a1][n] = qb[(size_t)a1 * N + n0 + n];
    }
    float* ksf = &ks[0][0];
    for (int idx = t; idx < NC * A; idx += 256)
        ksf[idx] = kb[(size_t)n0 * A + idx];
    __syncthreads();

    if constexpr (A == 16) {
        int a1 = t >> 4, a2 = t & 15;
        float s = 0.f;
#pragma unroll 8
        for (int n = 0; n < NC; n++) s += qs[a1][n] * ks[n][a2];
        atomicAdd(&logits[a1 * A + a2], s);
    } else {
        int a1  = t & 63;
        int a2b = (t >> 6) * 16;
        float acc[16];
#pragma unroll
        for (int j = 0; j < 16; j++) acc[j] = 0.f;
        for (int n = 0; n < NC; n++) {
            float q = qs[a1][n];
#pragma unroll
            for (int j = 0; j < 16; j++) acc[j] += q * ks[n][a2b + j];
        }
#pragma unroll
        for (int j = 0; j < 16; j++)
            atomicAdd(&logits[a1 * A + a2b + j], acc[j]);
    }
}

// ---------------------------------------------------------------------------
__global__ void softmax_kernel(const float* __restrict__ logits,
                               float* __restrict__ attn, int A)
{
    int row = blockIdx.x;      // a1
    int t = threadIdx.x;       // 64
    float l = (t < A) ? logits[row * A + t] : -INFINITY;
    float m = l;
#pragma unroll
    for (int off = 32; off > 0; off >>= 1) m = fmaxf(m, __shfl_xor(m, off, 64));
    float e = (t < A) ? expf(l - m) : 0.f;
    float s = e;
#pragma unroll
    for (int off = 32; off > 0; off >>= 1) s += __shfl_xor(s, off, 64);
    if (t < A) attn[row * A + t] = e / s;
}

// ---------------------------------------------------------------------------
// Kernel D (A=16), ONE batch: y[i] = g*sum_{a2<16} attn[t][a2]*v[m*16+a2] + x[i]
// with m = (c*64+w)*64+h, a1 = t.  fp32 x/y, bf16 v.
// ---------------------------------------------------------------------------
__global__ __launch_bounds__(256) void out16_kernel(
    const float* __restrict__ xb, const u16* __restrict__ vf,
    const float* __restrict__ attn, const float* __restrict__ gptr,
    float* __restrict__ yb)
{
    const u32 i = blockIdx.x * 256u + threadIdx.x;   // < CS = 2^23
    const float g = *gptr;
    const int h  = i & 63;
    const int w  = (i >> 6) & 63;
    const int tt = __builtin_amdgcn_readfirstlane((i >> 12) & 15);
    const int c  = (i >> 16) & 127;
    const int m  = (c * 64 + w) * 64 + h;

    const u16* vr = vf + (size_t)m * 16;
    const float* ar = attn + tt * 16;

    uint4 r0 = *(const uint4*)(vr);
    uint4 r1 = *(const uint4*)(vr + 8);
    float v0[8], v1[8];
    unpack8(r0, v0);
    unpack8(r1, v1);
    float4 a0 = *(const float4*)(ar);
    float4 a1 = *(const float4*)(ar + 4);
    float4 a2 = *(const float4*)(ar + 8);
    float4 a3 = *(const float4*)(ar + 12);

    float acc = v0[0]*a0.x + v0[1]*a0.y + v0[2]*a0.z + v0[3]*a0.w
              + v0[4]*a1.x + v0[5]*a1.y + v0[6]*a1.z + v0[7]*a1.w
              + v1[0]*a2.x + v1[1]*a2.y + v1[2]*a2.z + v1[3]*a2.w
              + v1[4]*a3.x + v1[5]*a3.y + v1[6]*a3.z + v1[7]*a3.w;

    yb[i] = g * acc + xb[i];
}

// ---------------------------------------------------------------------------
// Kernel D (A=64), ONE batch: thread handles 8 consecutive h (v-rows m0,m0+1).
// a1 = (h&3)*16 + t; m = (c*64+w)*16 + h/4.  fp32 x/y, bf16 v.
// ---------------------------------------------------------------------------
__global__ __launch_bounds__(256) void out64_kernel(
    const float* __restrict__ xb, const u16* __restrict__ vf,
    const float* __restrict__ attn, const float* __restrict__ gptr,
    float* __restrict__ yb)
{
    const u32 j = blockIdx.x * 256u + threadIdx.x;   // < CS/8 = 2^20
    const float g = *gptr;
    const int h8 = j & 7;
    const int w  = (j >> 3) & 63;
    const int tt = __builtin_amdgcn_readfirstlane((j >> 9) & 15);
    const int c  = __builtin_amdgcn_readfirstlane((j >> 13) & 127);

    const int m0 = (c * 64 + w) * 16 + h8 * 2;
    const u16* vr = vf + (size_t)m0 * 64;
    const float* ar0 = attn + tt * 64;               // a1 = 16*jj + tt -> + jj*1024

    float acc[8];
#pragma unroll
    for (int e = 0; e < 8; e++) acc[e] = 0.f;

#pragma unroll
    for (int a2b = 0; a2b < 64; a2b += 8) {
        uint4 ra = *(const uint4*)(vr + a2b);        // row m0
        uint4 rb = *(const uint4*)(vr + 64 + a2b);   // row m0+1
        float va[8], vb[8];
        unpack8(ra, va);
        unpack8(rb, vb);
#pragma unroll
        for (int jj = 0; jj < 4; jj++) {
            const float* ar = ar0 + jj * 1024 + a2b;
            float4 p0 = *(const float4*)(ar);
            float4 p1 = *(const float4*)(ar + 4);
            acc[jj]     += va[0]*p0.x + va[1]*p0.y + va[2]*p0.z + va[3]*p0.w
                         + va[4]*p1.x + va[5]*p1.y + va[6]*p1.z + va[7]*p1.w;
            acc[4 + jj] += vb[0]*p0.x + vb[1]*p0.y + vb[2]*p0.z + vb[3]*p0.w
                         + vb[4]*p1.x + vb[5]*p1.y + vb[6]*p1.z + vb[7]*p1.w;
        }
    }

    const size_t i0 = (((size_t)c * TDIM + tt) << 12) + ((size_t)w << 6) + (size_t)h8 * 8;
    float4 x0 = *(const float4*)(xb + i0);
    float4 x1 = *(const float4*)(xb + i0 + 4);
    float4 y0, y1;
    y0.x = g * acc[0] + x0.x; y0.y = g * acc[1] + x0.y;
    y0.z = g * acc[2] + x0.z; y0.w = g * acc[3] + x0.w;
    y1.x = g * acc[4] + x1.x; y1.y = g * acc[5] + x1.y;
    y1.z = g * acc[6] + x1.z; y1.w = g * acc[7] + x1.w;
    *(float4*)(yb + i0)     = y0;
    *(float4*)(yb + i0 + 4) = y1;
}

// ---------------------------------------------------------------------------
// Workspace (per-batch, reused across cells/batches): ~24.03 MiB total.
//   qf fp32 4 MiB | kf fp32 4 MiB | vf bf16 16 MiB | logits 16 KiB | attn 16 KiB
// ---------------------------------------------------------------------------
extern "C" void kernel_launch(void* const* d_in, const int* in_sizes, int n_in,
                              void* d_out, int out_size, void* d_ws, size_t ws_size,
                              hipStream_t stream)
{
    const float* x0    = (const float*)d_in[0];
    const float* Wq    = (const float*)d_in[1];
    const float* bq    = (const float*)d_in[2];
    const float* Wk    = (const float*)d_in[3];
    const float* bk    = (const float*)d_in[4];
    const float* Wv    = (const float*)d_in[5];
    const float* bv    = (const float*)d_in[6];
    const float* gamma = (const float*)d_in[7];
    float* y = (float*)d_out;

    char* ws = (char*)d_ws;
    float* qf     = (float*)(ws);                                // 4 MiB
    float* kf     = (float*)(ws + (size_t)(4  << 20));           // 4 MiB
    u16*   vf     = (u16*)  (ws + (size_t)(8  << 20));           // 16 MiB
    float* logits = (float*)(ws + (size_t)(24 << 20));           // 16 KiB
    float* attnp  = logits + 4096;                               // 16 KiB

    const int Adims[3] = { 16, 64, 64 };

    for (int cell = 0; cell < 3; cell++) {
        const int A = Adims[cell];
        const float* wq = Wq + cell * 16 * 128;
        const float* wk = Wk + cell * 16 * 128;
        const float* wv = Wv + cell * 128 * 128;

        for (int b = 0; b < BB; b++) {
            const float* xb = ((cell == 0) ? x0 : (const float*)y) + (size_t)b * CS;
            float* yb = y + (size_t)b * CS;

            qkv_kernel<<<SS / 64, 256, 0, stream>>>(
                xb, wq, bq + cell * 16, wk, bk + cell * 16, wv, bv + cell * 128,
                qf, kf, vf);

            zero_kernel<<<16, 256, 0, stream>>>(logits, 4096);

            if (A == 16)
                attn_logits_kernel<16><<<(CQ * SS / 16) / 64, 256, 0, stream>>>(qf, kf, logits);
            else
                attn_logits_kernel<64><<<(CQ * SS / 64) / 64, 256, 0, stream>>>(qf, kf, logits);

            softmax_kernel<<<A, 64, 0, stream>>>(logits, attnp, A);

            if (A == 16)
                out16_kernel<<<CS / 256, 256, 0, stream>>>(xb, vf, attnp, gamma + cell, yb);
            else
                out64_kernel<<<(CS / 8) / 256, 256, 0, stream>>>(xb, vf, attnp, gamma + cell, yb);
        }
    }
}

// Round 4
// 1678.740 us; speedup vs baseline: 1.3606x; 1.3606x over previous
//
#include <hip/hip_runtime.h>
#include <hip/hip_bf16.h>

#define BB 4
#define CC 128
#define CQ 16
#define TDIM 16
#define WDIM 64
#define HDIM 64
#define SS 65536            /* T*W*H */
#define CS (CC*SS)          /* per-batch elements: 8388608 */
#define NBLK 256            /* stage-1 partial blocks */

typedef unsigned short u16;
typedef unsigned int   u32;

__device__ __forceinline__ float bf2f(u16 v) { return __uint_as_float(((u32)v) << 16); }
__device__ __forceinline__ u16 f2bf(float f) {
    u32 u = __float_as_uint(f);
    u32 r = (u + 0x7fffu + ((u >> 16) & 1u)) >> 16;
    return (u16)r;
}
__device__ __forceinline__ void unpack8(uint4 r, float* f) {
    f[0] = __uint_as_float(r.x << 16); f[1] = __uint_as_float(r.x & 0xffff0000u);
    f[2] = __uint_as_float(r.y << 16); f[3] = __uint_as_float(r.y & 0xffff0000u);
    f[4] = __uint_as_float(r.z << 16); f[5] = __uint_as_float(r.z & 0xffff0000u);
    f[6] = __uint_as_float(r.w << 16); f[7] = __uint_as_float(r.w & 0xffff0000u);
}

// ---------------------------------------------------------------------------
// Kernel A: QKV 1x1 conv for ONE batch (fp32 I/O).
// q,k -> fp32 (cq, S); v -> bf16 (c, S) in workspace.
// ---------------------------------------------------------------------------
__global__ __launch_bounds__(256) void qkv_kernel(
    const float* __restrict__ xb,
    const float* __restrict__ Wq, const float* __restrict__ bq,
    const float* __restrict__ Wk, const float* __restrict__ bk,
    const float* __restrict__ Wv, const float* __restrict__ bv,
    float* __restrict__ qf, float* __restrict__ kf, u16* __restrict__ vf)
{
    __shared__ float lx[128 * 64];     // 32 KB
    const int t  = threadIdx.x;
    const int s0 = blockIdx.x << 6;    // 1024 blocks per batch

    for (int idx = t; idx < 128 * 64; idx += 256) {
        int c = idx >> 6, p = idx & 63;
        lx[idx] = xb[(size_t)c * SS + s0 + p];
    }
    __syncthreads();

    const int p8 = (t & 7) * 8;
    const int og = t >> 3;   // 0..31

    const float* wrow[5];
    float acc[5][8];
    {
        const float* w0 = (og < 16) ? (Wq + og * 128) : (Wk + (og - 16) * 128);
        float b0 = (og < 16) ? bq[og] : bk[og - 16];
        wrow[0] = w0;
#pragma unroll
        for (int j = 0; j < 8; j++) acc[0][j] = b0;
#pragma unroll
        for (int r = 1; r < 5; r++) {
            int vrow = og + 32 * (r - 1);
            wrow[r] = Wv + vrow * 128;
            float bias = bv[vrow];
#pragma unroll
            for (int j = 0; j < 8; j++) acc[r][j] = bias;
        }
    }

    for (int cb = 0; cb < 32; cb++) {
        float xv[32];
#pragma unroll
        for (int cc2 = 0; cc2 < 4; cc2++) {
            float4 raw = *(const float4*)(&lx[(cb * 4 + cc2) * 64 + p8]);
            xv[cc2 * 8 + 0] = raw.x; xv[cc2 * 8 + 1] = raw.y;
            xv[cc2 * 8 + 2] = raw.z; xv[cc2 * 8 + 3] = raw.w;
            float4 rw = *(const float4*)(&lx[(cb * 4 + cc2) * 64 + p8 + 4]);
            xv[cc2 * 8 + 4] = rw.x; xv[cc2 * 8 + 5] = rw.y;
            xv[cc2 * 8 + 6] = rw.z; xv[cc2 * 8 + 7] = rw.w;
        }
#pragma unroll
        for (int r = 0; r < 5; r++) {
            float4 wr = *(const float4*)(wrow[r] + cb * 4);
#pragma unroll
            for (int j = 0; j < 8; j++)
                acc[r][j] += wr.x * xv[j] + wr.y * xv[8 + j]
                           + wr.z * xv[16 + j] + wr.w * xv[24 + j];
        }
    }

    {
        float* dst = (og < 16) ? (qf + (size_t)og * SS + s0 + p8)
                               : (kf + (size_t)(og - 16) * SS + s0 + p8);
        *(float4*)(dst)     = make_float4(acc[0][0], acc[0][1], acc[0][2], acc[0][3]);
        *(float4*)(dst + 4) = make_float4(acc[0][4], acc[0][5], acc[0][6], acc[0][7]);
    }
#pragma unroll
    for (int r = 1; r < 5; r++) {
        int vrow = og + 32 * (r - 1);
        u16* dst = vf + (size_t)vrow * SS + s0 + p8;
        uint4 pk;
        pk.x = (u32)f2bf(acc[r][0]) | ((u32)f2bf(acc[r][1]) << 16);
        pk.y = (u32)f2bf(acc[r][2]) | ((u32)f2bf(acc[r][3]) << 16);
        pk.z = (u32)f2bf(acc[r][4]) | ((u32)f2bf(acc[r][5]) << 16);
        pk.w = (u32)f2bf(acc[r][6]) | ((u32)f2bf(acc[r][7]) << 16);
        *(uint4*)dst = pk;
    }
}

// ---------------------------------------------------------------------------
// Stage 1: per-block partial logits (no atomics).
// part[blk][..] layout: A=64 -> t*16+j encodes (a1 = t&63, a2 = (t>>6)*16+j);
//                       A=16 -> t      encodes (a1 = t>>4, a2 = t&15).
// ---------------------------------------------------------------------------
template <int A>
__global__ __launch_bounds__(256) void logits_part_kernel(
    const float* __restrict__ qb, const float* __restrict__ kb,
    float* __restrict__ part)
{
    constexpr int N = (CQ * SS) / A;
    constexpr int NCHUNK = N / NBLK;         // A=64 -> 64, A=16 -> 256
    constexpr int NLOG = (NCHUNK == 64) ? 6 : 8;
    __shared__ float qs[A][NCHUNK + 1];
    __shared__ float ks[NCHUNK][A];
    const int t  = threadIdx.x;
    const int n0 = blockIdx.x << NLOG;

    for (int idx = t; idx < A * NCHUNK; idx += 256) {
        int a1 = idx >> NLOG, n = idx & (NCHUNK - 1);
        qs[a1][n] = qb[(size_t)a1 * N + n0 + n];
    }
    float* ksf = &ks[0][0];
    for (int idx = t; idx < NCHUNK * A; idx += 256)
        ksf[idx] = kb[(size_t)n0 * A + idx];
    __syncthreads();

    float* pb = part + (size_t)blockIdx.x * (A * A);

    if constexpr (A == 16) {
        int a1 = t >> 4, a2 = t & 15;
        float s = 0.f;
#pragma unroll 8
        for (int n = 0; n < NCHUNK; n++) s += qs[a1][n] * ks[n][a2];
        pb[t] = s;
    } else {
        int a1  = t & 63;
        int a2b = (t >> 6) * 16;
        float acc[16];
#pragma unroll
        for (int j = 0; j < 16; j++) acc[j] = 0.f;
        for (int n = 0; n < NCHUNK; n++) {
            float q = qs[a1][n];
#pragma unroll
            for (int j = 0; j < 16; j++) acc[j] += q * ks[n][a2b + j];
        }
        float* dst = pb + t * 16;            // coalesced
        *(float4*)(dst)      = make_float4(acc[0],  acc[1],  acc[2],  acc[3]);
        *(float4*)(dst + 4)  = make_float4(acc[4],  acc[5],  acc[6],  acc[7]);
        *(float4*)(dst + 8)  = make_float4(acc[8],  acc[9],  acc[10], acc[11]);
        *(float4*)(dst + 12) = make_float4(acc[12], acc[13], acc[14], acc[15]);
    }
}

// ---------------------------------------------------------------------------
// Stage 2: reduce partials over NBLK blocks + softmax.  grid = A, block = 64.
// ---------------------------------------------------------------------------
template <int A>
__global__ __launch_bounds__(64) void reduce_softmax_kernel(
    const float* __restrict__ part, float* __restrict__ attn)
{
    const int a1 = blockIdx.x;
    const int t  = threadIdx.x;

    int off;
    if constexpr (A == 16) off = a1 * 16 + t;                       // t = a2 (<16)
    else                   off = (t & 15) + ((a1 + (t >> 4) * 64) << 4);

    float l;
    if (A == 16 && t >= 16) {
        l = -INFINITY;
    } else {
        float s0 = 0.f, s1 = 0.f, s2 = 0.f, s3 = 0.f;
#pragma unroll 4
        for (int blk = 0; blk < NBLK; blk += 4) {
            s0 += part[(size_t)(blk + 0) * (A * A) + off];
            s1 += part[(size_t)(blk + 1) * (A * A) + off];
            s2 += part[(size_t)(blk + 2) * (A * A) + off];
            s3 += part[(size_t)(blk + 3) * (A * A) + off];
        }
        l = (s0 + s1) + (s2 + s3);
    }

    float m = l;
#pragma unroll
    for (int off2 = 32; off2 > 0; off2 >>= 1) m = fmaxf(m, __shfl_xor(m, off2, 64));
    float e = (A == 16 && t >= 16) ? 0.f : expf(l - m);
    float s = e;
#pragma unroll
    for (int off2 = 32; off2 > 0; off2 >>= 1) s += __shfl_xor(s, off2, 64);
    if (t < A) attn[a1 * A + t] = e / s;
}

// ---------------------------------------------------------------------------
// Kernel D (A=16), ONE batch.
// ---------------------------------------------------------------------------
__global__ __launch_bounds__(256) void out16_kernel(
    const float* __restrict__ xb, const u16* __restrict__ vf,
    const float* __restrict__ attn, const float* __restrict__ gptr,
    float* __restrict__ yb)
{
    const u32 i = blockIdx.x * 256u + threadIdx.x;   // < CS = 2^23
    const float g = *gptr;
    const int h  = i & 63;
    const int w  = (i >> 6) & 63;
    const int tt = __builtin_amdgcn_readfirstlane((i >> 12) & 15);
    const int c  = (i >> 16) & 127;
    const int m  = (c * 64 + w) * 64 + h;

    const u16* vr = vf + (size_t)m * 16;
    const float* ar = attn + tt * 16;

    uint4 r0 = *(const uint4*)(vr);
    uint4 r1 = *(const uint4*)(vr + 8);
    float v0[8], v1[8];
    unpack8(r0, v0);
    unpack8(r1, v1);
    float4 a0 = *(const float4*)(ar);
    float4 a1 = *(const float4*)(ar + 4);
    float4 a2 = *(const float4*)(ar + 8);
    float4 a3 = *(const float4*)(ar + 12);

    float acc = v0[0]*a0.x + v0[1]*a0.y + v0[2]*a0.z + v0[3]*a0.w
              + v0[4]*a1.x + v0[5]*a1.y + v0[6]*a1.z + v0[7]*a1.w
              + v1[0]*a2.x + v1[1]*a2.y + v1[2]*a2.z + v1[3]*a2.w
              + v1[4]*a3.x + v1[5]*a3.y + v1[6]*a3.z + v1[7]*a3.w;

    yb[i] = g * acc + xb[i];
}

// ---------------------------------------------------------------------------
// Kernel D (A=64), ONE batch.
// ---------------------------------------------------------------------------
__global__ __launch_bounds__(256) void out64_kernel(
    const float* __restrict__ xb, const u16* __restrict__ vf,
    const float* __restrict__ attn, const float* __restrict__ gptr,
    float* __restrict__ yb)
{
    const u32 j = blockIdx.x * 256u + threadIdx.x;   // < CS/8 = 2^20
    const float g = *gptr;
    const int h8 = j & 7;
    const int w  = (j >> 3) & 63;
    const int tt = __builtin_amdgcn_readfirstlane((j >> 9) & 15);
    const int c  = __builtin_amdgcn_readfirstlane((j >> 13) & 127);

    const int m0 = (c * 64 + w) * 16 + h8 * 2;
    const u16* vr = vf + (size_t)m0 * 64;
    const float* ar0 = attn + tt * 64;               // a1 = 16*jj + tt -> + jj*1024

    float acc[8];
#pragma unroll
    for (int e = 0; e < 8; e++) acc[e] = 0.f;

#pragma unroll
    for (int a2b = 0; a2b < 64; a2b += 8) {
        uint4 ra = *(const uint4*)(vr + a2b);
        uint4 rb = *(const uint4*)(vr + 64 + a2b);
        float va[8], vb[8];
        unpack8(ra, va);
        unpack8(rb, vb);
#pragma unroll
        for (int jj = 0; jj < 4; jj++) {
            const float* ar = ar0 + jj * 1024 + a2b;
            float4 p0 = *(const float4*)(ar);
            float4 p1 = *(const float4*)(ar + 4);
            acc[jj]     += va[0]*p0.x + va[1]*p0.y + va[2]*p0.z + va[3]*p0.w
                         + va[4]*p1.x + va[5]*p1.y + va[6]*p1.z + va[7]*p1.w;
            acc[4 + jj] += vb[0]*p0.x + vb[1]*p0.y + vb[2]*p0.z + vb[3]*p0.w
                         + vb[4]*p1.x + vb[5]*p1.y + vb[6]*p1.z + vb[7]*p1.w;
        }
    }

    const size_t i0 = (((size_t)c * TDIM + tt) << 12) + ((size_t)w << 6) + (size_t)h8 * 8;
    float4 x0 = *(const float4*)(xb + i0);
    float4 x1 = *(const float4*)(xb + i0 + 4);
    float4 y0, y1;
    y0.x = g * acc[0] + x0.x; y0.y = g * acc[1] + x0.y;
    y0.z = g * acc[2] + x0.z; y0.w = g * acc[3] + x0.w;
    y1.x = g * acc[4] + x1.x; y1.y = g * acc[5] + x1.y;
    y1.z = g * acc[6] + x1.z; y1.w = g * acc[7] + x1.w;
    *(float4*)(yb + i0)     = y0;
    *(float4*)(yb + i0 + 4) = y1;
}

// ---------------------------------------------------------------------------
// Workspace (per-batch, reused): qf 4M | kf 4M | vf 16M | part 4M | attn 16K
// Total ~28.02 MiB.
// ---------------------------------------------------------------------------
extern "C" void kernel_launch(void* const* d_in, const int* in_sizes, int n_in,
                              void* d_out, int out_size, void* d_ws, size_t ws_size,
                              hipStream_t stream)
{
    const float* x0    = (const float*)d_in[0];
    const float* Wq    = (const float*)d_in[1];
    const float* bq    = (const float*)d_in[2];
    const float* Wk    = (const float*)d_in[3];
    const float* bk    = (const float*)d_in[4];
    const float* Wv    = (const float*)d_in[5];
    const float* bv    = (const float*)d_in[6];
    const float* gamma = (const float*)d_in[7];
    float* y = (float*)d_out;

    char* ws = (char*)d_ws;
    float* qf    = (float*)(ws);                                // 4 MiB
    float* kf    = (float*)(ws + (size_t)(4  << 20));           // 4 MiB
    u16*   vf    = (u16*)  (ws + (size_t)(8  << 20));           // 16 MiB
    float* part  = (float*)(ws + (size_t)(24 << 20));           // 4 MiB
    float* attnp = (float*)(ws + (size_t)(28 << 20));           // 16 KiB

    const int Adims[3] = { 16, 64, 64 };

    for (int cell = 0; cell < 3; cell++) {
        const int A = Adims[cell];
        const float* wq = Wq + cell * 16 * 128;
        const float* wk = Wk + cell * 16 * 128;
        const float* wv = Wv + cell * 128 * 128;

        for (int b = 0; b < BB; b++) {
            const float* xb = ((cell == 0) ? x0 : (const float*)y) + (size_t)b * CS;
            float* yb = y + (size_t)b * CS;

            qkv_kernel<<<SS / 64, 256, 0, stream>>>(
                xb, wq, bq + cell * 16, wk, bk + cell * 16, wv, bv + cell * 128,
                qf, kf, vf);

            if (A == 16) {
                logits_part_kernel<16><<<NBLK, 256, 0, stream>>>(qf, kf, part);
                reduce_softmax_kernel<16><<<16, 64, 0, stream>>>(part, attnp);
                out16_kernel<<<CS / 256, 256, 0, stream>>>(xb, vf, attnp, gamma + cell, yb);
            } else {
                logits_part_kernel<64><<<NBLK, 256, 0, stream>>>(qf, kf, part);
                reduce_softmax_kernel<64><<<64, 64, 0, stream>>>(part, attnp);
                out64_kernel<<<(CS / 8) / 256, 256, 0, stream>>>(xb, vf, attnp, gamma + cell, yb);
            }
        }
    }
}